// Round 1
// baseline (116.341 us; speedup 1.0000x reference)
//
#include <hip/hip_runtime.h>
#include <math.h>

#define NP 400
#define NV 204
#define STEP 20
#define HW 4096
#define BS 8
#define NBLK (NV * BS)   // 1632 partials

// ws layout:
//   [0,4)                     : uint counter (zeroed by pre_kernel each launch)
//   [64, 64 + BS*NP*16)       : float4 gw[b][q] = (gx,gy,gz,|g|^2)  (51200 B)
//   [64 + 51200, + NBLK*4)    : partials (6528 B)
//
// Structure change vs previous version:
//  - pre_kernel (8 blocks) computes the gt-transformed cloud ONCE per b into
//    global ws (was: recomputed + LDS-staged by all 1632 blocks). The sym
//    inner loop now reads it with wave-uniform addresses -> scalar/L1
//    broadcast loads instead of ds_read_b128 broadcasts. The old loop was
//    DS-pipe-issue-bound (~192 DS cyc vs 64 VALU cyc per 4-q group, 4 waves);
//    now it is VALU-bound (~6400 cyc/block).
//  - finalize_kernel dispatch removed: last-arriving block (device-scope
//    counter) reduces the partials and writes out[0]. Dispatches: 2 -> 2,
//    but the big kernel's tail no longer waits for a third launch gap.
//  - non-sym blocks: no LDS staging, no staging barrier at all.

__global__ __launch_bounds__(256) void pre_kernel(
    const float* __restrict__ gt_r,      // (8,3,3)
    const float* __restrict__ gt_t,      // (8,3)
    const float* __restrict__ model_xyz, // (8,3,400)
    float4* __restrict__ gw,             // (8,400)
    unsigned* __restrict__ counter)
{
    const int b   = blockIdx.x;  // 0..7
    const int tid = threadIdx.x;
    if (b == 0 && tid == 0) *counter = 0u;  // kernel-boundary release makes this visible

    const float g00 = gt_r[b*9+0], g01 = gt_r[b*9+1], g02 = gt_r[b*9+2];
    const float g10 = gt_r[b*9+3], g11 = gt_r[b*9+4], g12 = gt_r[b*9+5];
    const float g20 = gt_r[b*9+6], g21 = gt_r[b*9+7], g22 = gt_r[b*9+8];
    const float gtx = gt_t[b*3+0], gty = gt_t[b*3+1], gtz = gt_t[b*3+2];
    const float* mb = model_xyz + (size_t)b * 3 * NP;

    for (int q = tid; q < NP; q += 256) {
        float mx = mb[q], my = mb[NP+q], mz = mb[2*NP+q];
        float gx = g00*mx + g01*my + g02*mz + gtx;
        float gy = g10*mx + g11*my + g12*mz + gty;
        float gz = g20*mx + g21*my + g22*mz + gtz;
        gw[b*NP + q] = make_float4(gx, gy, gz, gx*gx + gy*gy + gz*gz);
    }
}

__global__ __launch_bounds__(256) void main_kernel(
    const float* __restrict__ pred_r,    // (8,4,4096)
    const float* __restrict__ pred_t,    // (8,3,4096)
    const float* __restrict__ pred_score,// (8,4096)
    const int*   __restrict__ cls_ids,   // (8,)
    const float* __restrict__ model_xyz, // (8,3,400)
    const float4* __restrict__ gw,       // (8,400) precomputed gt points
    float* __restrict__ partials,        // (1632,)
    unsigned* __restrict__ counter,
    float* __restrict__ out)
{
    const int v   = blockIdx.x;   // 0..203
    const int b   = blockIdx.y;   // 0..7
    const int tid = threadIdx.x;  // 0..255
    const int pix = v * STEP;

    __shared__ float s_part[4];
    __shared__ int   s_last;

    const int  cls   = cls_ids[b];
    const bool sym   = (cls==12)||(cls==15)||(cls==18)||(cls==19)||(cls==20);
    const bool valid = (cls+1 >= 1) && (cls+1 <= 30); // SELECT_ID = 1..30
    const bool has2  = (tid < NP - 256);              // tid < 144

    const float*  mb  = model_xyz + (size_t)b * 3 * NP;
    const float4* gwb = gw + b * NP;

    // ---- quaternion -> rotation (uniform per block; scalar loads) ----
    float q0 = pred_r[((size_t)b*4+0)*HW + pix];
    float q1 = pred_r[((size_t)b*4+1)*HW + pix];
    float q2 = pred_r[((size_t)b*4+2)*HW + pix];
    float q3 = pred_r[((size_t)b*4+3)*HW + pix];
    {
        float inv = 1.0f / sqrtf(q0*q0 + q1*q1 + q2*q2 + q3*q3);
        q0 *= inv; q1 *= inv; q2 *= inv; q3 *= inv;
    }
    const float R00 = 1.0f - 2.0f*(q2*q2 + q3*q3);
    const float R01 = 2.0f*q1*q2 - 2.0f*q0*q3;
    const float R02 = 2.0f*q0*q2 + 2.0f*q1*q3;
    const float R10 = 2.0f*q1*q2 + 2.0f*q3*q0;
    const float R11 = 1.0f - 2.0f*(q1*q1 + q3*q3);
    const float R12 = -2.0f*q0*q1 + 2.0f*q2*q3;
    const float R20 = -2.0f*q0*q2 + 2.0f*q1*q3;
    const float R21 = 2.0f*q0*q1 + 2.0f*q2*q3;
    const float R22 = 1.0f - 2.0f*(q1*q1 + q2*q2);

    const float ptx = pred_t[((size_t)b*3+0)*HW + pix];
    const float pty = pred_t[((size_t)b*3+1)*HW + pix];
    const float ptz = pred_t[((size_t)b*3+2)*HW + pix];

    // ---- this thread's predicted points ----
    const int p0 = tid;
    const int p1 = has2 ? tid + 256 : tid;
    float mx0 = mb[p0], my0 = mb[NP+p0], mz0 = mb[2*NP+p0];
    float mx1 = mb[p1], my1 = mb[NP+p1], mz1 = mb[2*NP+p1];
    const float px0 = R00*mx0 + R01*my0 + R02*mz0 + ptx;
    const float py0 = R10*mx0 + R11*my0 + R12*mz0 + pty;
    const float pz0 = R20*mx0 + R21*my0 + R22*mz0 + ptz;
    const float px1 = R00*mx1 + R01*my1 + R02*mz1 + ptx;
    const float py1 = R10*mx1 + R11*my1 + R12*mz1 + pty;
    const float pz1 = R20*mx1 + R21*my1 + R22*mz1 + ptz;

    float d2_0, d2_1;
    if (sym) {
        // d2 = pn + (gn - 2*dot); min over q. gwb[q] is wave-uniform -> no DS pipe.
        // All 4 waves run the dual-point loop (lanes >=144 compute a dup that is
        // discarded); keeps the loop in uniform control flow so the uniform
        // loads can scalarize.
        const float nx0 = -2.0f*px0, ny0 = -2.0f*py0, nz0 = -2.0f*pz0;
        const float pn0 = px0*px0 + py0*py0 + pz0*pz0;
        const float nx1 = -2.0f*px1, ny1 = -2.0f*py1, nz1 = -2.0f*pz1;
        const float pn1 = px1*px1 + py1*py1 + pz1*pz1;
        float a0 = 3.4e38f, a1 = 3.4e38f, a2 = 3.4e38f, a3 = 3.4e38f;
        float c0 = 3.4e38f, c1 = 3.4e38f, c2 = 3.4e38f, c3 = 3.4e38f;
        for (int q = 0; q < NP; q += 4) {
            const float4 g0 = gwb[q+0], g1 = gwb[q+1];
            const float4 g2 = gwb[q+2], g3 = gwb[q+3];
            a0 = fminf(a0, fmaf(nx0, g0.x, fmaf(ny0, g0.y, fmaf(nz0, g0.z, g0.w))));
            a1 = fminf(a1, fmaf(nx0, g1.x, fmaf(ny0, g1.y, fmaf(nz0, g1.z, g1.w))));
            a2 = fminf(a2, fmaf(nx0, g2.x, fmaf(ny0, g2.y, fmaf(nz0, g2.z, g2.w))));
            a3 = fminf(a3, fmaf(nx0, g3.x, fmaf(ny0, g3.y, fmaf(nz0, g3.z, g3.w))));
            c0 = fminf(c0, fmaf(nx1, g0.x, fmaf(ny1, g0.y, fmaf(nz1, g0.z, g0.w))));
            c1 = fminf(c1, fmaf(nx1, g1.x, fmaf(ny1, g1.y, fmaf(nz1, g1.z, g1.w))));
            c2 = fminf(c2, fmaf(nx1, g2.x, fmaf(ny1, g2.y, fmaf(nz1, g2.z, g2.w))));
            c3 = fminf(c3, fmaf(nx1, g3.x, fmaf(ny1, g3.y, fmaf(nz1, g3.z, g3.w))));
        }
        d2_0 = fmaxf(pn0 + fminf(fminf(a0, a1), fminf(a2, a3)), 0.0f);
        d2_1 = fmaxf(pn1 + fminf(fminf(c0, c1), fminf(c2, c3)), 0.0f);
    } else {
        // ADD path: direct differences against own gt point (per-thread load)
        float4 g = gwb[p0];
        float dx = px0 - g.x, dy = py0 - g.y, dz = pz0 - g.z;
        d2_0 = dx*dx + dy*dy + dz*dz;
        g = gwb[p1];
        dx = px1 - g.x; dy = py1 - g.y; dz = pz1 - g.z;
        d2_1 = dx*dx + dy*dy + dz*dz;
    }
    float local = sqrtf(d2_0) + (has2 ? sqrtf(d2_1) : 0.0f);

    // ---- block reduction (4 waves of 64) ----
    #pragma unroll
    for (int off = 32; off > 0; off >>= 1)
        local += __shfl_down(local, off, 64);
    const int wave = tid >> 6;
    if ((tid & 63) == 0) s_part[wave] = local;
    __syncthreads();

    if (tid == 0) {
        float tot  = s_part[0] + s_part[1] + s_part[2] + s_part[3];
        float mean = tot * (1.0f / NP);                 // add_ij[b,v]
        float ps   = pred_score[(size_t)b*HW + pix];
        float c = 0.0f;
        if (valid)
            c = (mean * ps - 0.01f * logf(ps)) * (1.0f / NBLK);
        // release-store partial, then bump the arrival counter
        __hip_atomic_store(&partials[b * NV + v], c,
                           __ATOMIC_RELEASE, __HIP_MEMORY_SCOPE_AGENT);
        unsigned prev = __hip_atomic_fetch_add(counter, 1u,
                           __ATOMIC_ACQ_REL, __HIP_MEMORY_SCOPE_AGENT);
        s_last = (prev == NBLK - 1) ? 1 : 0;
    }
    __syncthreads();

    // ---- last-arriving block performs the grid reduction ----
    if (s_last) {
        float acc = 0.0f;
        for (int i = tid; i < NBLK; i += 256)
            acc += __hip_atomic_load(&partials[i],
                       __ATOMIC_RELAXED, __HIP_MEMORY_SCOPE_AGENT);
        #pragma unroll
        for (int off = 32; off > 0; off >>= 1)
            acc += __shfl_down(acc, off, 64);
        if ((tid & 63) == 0) s_part[tid >> 6] = acc;
        __syncthreads();
        if (tid == 0) {
            float vv = s_part[0] + s_part[1] + s_part[2] + s_part[3];
            if (isnan(vv) || isinf(vv)) vv = 0.0f;
            out[0] = vv;   // gadd_loss + 0*gadd == gadd_loss
        }
    }
}

extern "C" void kernel_launch(void* const* d_in, const int* in_sizes, int n_in,
                              void* d_out, int out_size, void* d_ws, size_t ws_size,
                              hipStream_t stream) {
    const float* pred_r     = (const float*)d_in[0];
    const float* pred_t     = (const float*)d_in[1];
    const float* pred_score = (const float*)d_in[2];
    const float* gt_r       = (const float*)d_in[3];
    const float* gt_t       = (const float*)d_in[4];
    const int*   cls_ids    = (const int*)d_in[5];
    const float* model_xyz  = (const float*)d_in[6];
    float* out = (float*)d_out;

    unsigned* counter  = (unsigned*)d_ws;
    float4*   gw       = (float4*)((char*)d_ws + 64);
    float*    partials = (float*)((char*)d_ws + 64 + (size_t)BS * NP * sizeof(float4));

    pre_kernel<<<dim3(BS), 256, 0, stream>>>(gt_r, gt_t, model_xyz, gw, counter);

    dim3 grid(NV, BS);
    main_kernel<<<grid, 256, 0, stream>>>(pred_r, pred_t, pred_score, cls_ids,
                                          model_xyz, gw, partials, counter, out);
}

// Round 2
// 90.975 us; speedup vs baseline: 1.2788x; 1.2788x over previous
//
#include <hip/hip_runtime.h>
#include <math.h>

#define NP 400
#define NV 204
#define STEP 20
#define HW 4096
#define BS 8
#define NBLK (NV * BS)   // 1632 blocks

// Round-2 structure:
//  - Compute body reverted to the round-0 LDS-staged form (proven ~10 us class;
//    round-1's global-uniform-load loop was latency-bound at 53 us, VALUBusy 3%).
//  - NO d_ws usage anywhere. Round-0/1 counters showed a 256-MiB
//    fillBufferAligned (40 us, WRITE_SIZE=262144 KB) once per timed iteration:
//    the workspace re-poison dominates the measurement. Avoiding d_ws should
//    drop it from the timed graph.
//  - Reduction: hipMemsetAsync zeroes out[0]; each block tid0 does one
//    device-scope atomicAdd (1632 same-address f32 atomics, overlapped with
//    compute of later blocks); a 1-thread fix kernel applies the reference's
//    isnan/isinf -> 0 rule.

__global__ __launch_bounds__(256) void partial_kernel(
    const float* __restrict__ pred_r,    // (8,4,4096)
    const float* __restrict__ pred_t,    // (8,3,4096)
    const float* __restrict__ pred_score,// (8,4096)
    const float* __restrict__ gt_r,      // (8,3,3)
    const float* __restrict__ gt_t,      // (8,3)
    const int*   __restrict__ cls_ids,   // (8,)
    const float* __restrict__ model_xyz, // (8,3,400)
    float* __restrict__ out)             // (1,) pre-zeroed
{
    const int v   = blockIdx.x;   // 0..203
    const int b   = blockIdx.y;   // 0..7
    const int tid = threadIdx.x;  // 0..255
    const int pix = v * STEP;

    __shared__ float4 s_g[NP];    // (gx, gy, gz, gn) per gt point
    __shared__ float  s_part[4];

    const int   cls = cls_ids[b];
    const bool  sym = (cls==12)||(cls==15)||(cls==18)||(cls==19)||(cls==20);
    const bool  valid = (cls+1 >= 1) && (cls+1 <= 30); // SELECT_ID = 1..30
    const bool  has2 = (tid < NP - 256);               // tid < 144

    const float* mb = model_xyz + (size_t)b * 3 * NP;

    // ---- stage gt-transformed points (+ squared norm) in LDS ----
    {
        const float g00 = gt_r[b*9+0], g01 = gt_r[b*9+1], g02 = gt_r[b*9+2];
        const float g10 = gt_r[b*9+3], g11 = gt_r[b*9+4], g12 = gt_r[b*9+5];
        const float g20 = gt_r[b*9+6], g21 = gt_r[b*9+7], g22 = gt_r[b*9+8];
        const float gtx = gt_t[b*3+0], gty = gt_t[b*3+1], gtz = gt_t[b*3+2];
        for (int q = tid; q < NP; q += 256) {
            float mx = mb[q], my = mb[NP+q], mz = mb[2*NP+q];
            float gx = g00*mx + g01*my + g02*mz + gtx;
            float gy = g10*mx + g11*my + g12*mz + gty;
            float gz = g20*mx + g21*my + g22*mz + gtz;
            s_g[q] = make_float4(gx, gy, gz, gx*gx + gy*gy + gz*gz);
        }
    }

    // ---- quaternion -> rotation (uniform per block) ----
    float q0 = pred_r[((size_t)b*4+0)*HW + pix];
    float q1 = pred_r[((size_t)b*4+1)*HW + pix];
    float q2 = pred_r[((size_t)b*4+2)*HW + pix];
    float q3 = pred_r[((size_t)b*4+3)*HW + pix];
    {
        float inv = 1.0f / sqrtf(q0*q0 + q1*q1 + q2*q2 + q3*q3);
        q0 *= inv; q1 *= inv; q2 *= inv; q3 *= inv;
    }
    const float R00 = 1.0f - 2.0f*(q2*q2 + q3*q3);
    const float R01 = 2.0f*q1*q2 - 2.0f*q0*q3;
    const float R02 = 2.0f*q0*q2 + 2.0f*q1*q3;
    const float R10 = 2.0f*q1*q2 + 2.0f*q3*q0;
    const float R11 = 1.0f - 2.0f*(q1*q1 + q3*q3);
    const float R12 = -2.0f*q0*q1 + 2.0f*q2*q3;
    const float R20 = -2.0f*q0*q2 + 2.0f*q1*q3;
    const float R21 = 2.0f*q0*q1 + 2.0f*q2*q3;
    const float R22 = 1.0f - 2.0f*(q1*q1 + q2*q2);

    const float ptx = pred_t[((size_t)b*3+0)*HW + pix];
    const float pty = pred_t[((size_t)b*3+1)*HW + pix];
    const float ptz = pred_t[((size_t)b*3+2)*HW + pix];

    __syncthreads();

    // ---- predicted points for this thread's p's ----
    const int p0 = tid;
    const int p1 = has2 ? tid + 256 : tid;
    float mx0 = mb[p0], my0 = mb[NP+p0], mz0 = mb[2*NP+p0];
    float mx1 = mb[p1], my1 = mb[NP+p1], mz1 = mb[2*NP+p1];
    const float px0 = R00*mx0 + R01*my0 + R02*mz0 + ptx;
    const float py0 = R10*mx0 + R11*my0 + R12*mz0 + pty;
    const float pz0 = R20*mx0 + R21*my0 + R22*mz0 + ptz;
    const float px1 = R00*mx1 + R01*my1 + R02*mz1 + ptx;
    const float py1 = R10*mx1 + R11*my1 + R12*mz1 + pty;
    const float pz1 = R20*mx1 + R21*my1 + R22*mz1 + ptz;

    float d2_0 = 0.0f, d2_1 = 0.0f;
    if (sym) {
        const float nx0 = -2.0f*px0, ny0 = -2.0f*py0, nz0 = -2.0f*pz0;
        const float pn0 = px0*px0 + py0*py0 + pz0*pz0;
        if (tid < 192) {
            // waves 0..2: two points per thread (lanes 144..191 compute a dup)
            const float nx1 = -2.0f*px1, ny1 = -2.0f*py1, nz1 = -2.0f*pz1;
            const float pn1 = px1*px1 + py1*py1 + pz1*pz1;
            float a0 = 3.4e38f, a1 = 3.4e38f, a2 = 3.4e38f, a3 = 3.4e38f;
            float c0 = 3.4e38f, c1 = 3.4e38f, c2 = 3.4e38f, c3 = 3.4e38f;
            for (int q = 0; q < NP; q += 4) {
                const float4 g0 = s_g[q+0], g1 = s_g[q+1];
                const float4 g2 = s_g[q+2], g3 = s_g[q+3];
                a0 = fminf(a0, fmaf(nx0, g0.x, fmaf(ny0, g0.y, fmaf(nz0, g0.z, g0.w))));
                a1 = fminf(a1, fmaf(nx0, g1.x, fmaf(ny0, g1.y, fmaf(nz0, g1.z, g1.w))));
                a2 = fminf(a2, fmaf(nx0, g2.x, fmaf(ny0, g2.y, fmaf(nz0, g2.z, g2.w))));
                a3 = fminf(a3, fmaf(nx0, g3.x, fmaf(ny0, g3.y, fmaf(nz0, g3.z, g3.w))));
                c0 = fminf(c0, fmaf(nx1, g0.x, fmaf(ny1, g0.y, fmaf(nz1, g0.z, g0.w))));
                c1 = fminf(c1, fmaf(nx1, g1.x, fmaf(ny1, g1.y, fmaf(nz1, g1.z, g1.w))));
                c2 = fminf(c2, fmaf(nx1, g2.x, fmaf(ny1, g2.y, fmaf(nz1, g2.z, g2.w))));
                c3 = fminf(c3, fmaf(nx1, g3.x, fmaf(ny1, g3.y, fmaf(nz1, g3.z, g3.w))));
            }
            d2_0 = fmaxf(pn0 + fminf(fminf(a0, a1), fminf(a2, a3)), 0.0f);
            d2_1 = fmaxf(pn1 + fminf(fminf(c0, c1), fminf(c2, c3)), 0.0f);
        } else {
            // wave 3: single point per thread — half the work
            float a0 = 3.4e38f, a1 = 3.4e38f, a2 = 3.4e38f, a3 = 3.4e38f;
            for (int q = 0; q < NP; q += 4) {
                const float4 g0 = s_g[q+0], g1 = s_g[q+1];
                const float4 g2 = s_g[q+2], g3 = s_g[q+3];
                a0 = fminf(a0, fmaf(nx0, g0.x, fmaf(ny0, g0.y, fmaf(nz0, g0.z, g0.w))));
                a1 = fminf(a1, fmaf(nx0, g1.x, fmaf(ny0, g1.y, fmaf(nz0, g1.z, g1.w))));
                a2 = fminf(a2, fmaf(nx0, g2.x, fmaf(ny0, g2.y, fmaf(nz0, g2.z, g2.w))));
                a3 = fminf(a3, fmaf(nx0, g3.x, fmaf(ny0, g3.y, fmaf(nz0, g3.z, g3.w))));
            }
            d2_0 = fmaxf(pn0 + fminf(fminf(a0, a1), fminf(a2, a3)), 0.0f);
            d2_1 = 0.0f;
        }
    } else {
        // ADD path: reference uses direct differences
        float4 g = s_g[p0];
        float dx = px0 - g.x, dy = py0 - g.y, dz = pz0 - g.z;
        d2_0 = dx*dx + dy*dy + dz*dz;
        g = s_g[p1];
        dx = px1 - g.x; dy = py1 - g.y; dz = pz1 - g.z;
        d2_1 = dx*dx + dy*dy + dz*dz;
    }
    float local = sqrtf(d2_0) + (has2 ? sqrtf(d2_1) : 0.0f);

    // ---- block reduction (4 waves of 64) ----
    #pragma unroll
    for (int off = 32; off > 0; off >>= 1)
        local += __shfl_down(local, off, 64);
    const int wave = tid >> 6;
    if ((tid & 63) == 0) s_part[wave] = local;
    __syncthreads();
    if (tid == 0) {
        float tot  = s_part[0] + s_part[1] + s_part[2] + s_part[3];
        float mean = tot * (1.0f / NP);                 // add_ij[b,v]
        float ps   = pred_score[(size_t)b*HW + pix];
        if (valid) {
            float c = (mean * ps - 0.01f * logf(ps)) * (1.0f / NBLK);
            atomicAdd(out, c);   // device-scope by default on CDNA
        }
    }
}

__global__ void fix_kernel(float* __restrict__ out)
{
    float vv = out[0];
    if (isnan(vv) || isinf(vv)) out[0] = 0.0f;  // reference's bad-loss guard
}

extern "C" void kernel_launch(void* const* d_in, const int* in_sizes, int n_in,
                              void* d_out, int out_size, void* d_ws, size_t ws_size,
                              hipStream_t stream) {
    const float* pred_r     = (const float*)d_in[0];
    const float* pred_t     = (const float*)d_in[1];
    const float* pred_score = (const float*)d_in[2];
    const float* gt_r       = (const float*)d_in[3];
    const float* gt_t       = (const float*)d_in[4];
    const int*   cls_ids    = (const int*)d_in[5];
    const float* model_xyz  = (const float*)d_in[6];
    float* out = (float*)d_out;

    // d_ws deliberately untouched: the 256-MiB workspace re-poison fill
    // (40 us/iter in rocprof) was the dominant timed cost.
    hipMemsetAsync(out, 0, sizeof(float), stream);

    dim3 grid(NV, BS);
    partial_kernel<<<grid, 256, 0, stream>>>(pred_r, pred_t, pred_score,
                                             gt_r, gt_t, cls_ids, model_xyz, out);
    fix_kernel<<<1, 1, 0, stream>>>(out);
}

// Round 3
// 70.290 us; speedup vs baseline: 1.6551x; 1.2943x over previous
//
#include <hip/hip_runtime.h>
#include <math.h>

#define NP 400
#define NV 204
#define STEP 20
#define HW 4096
#define BS 8
#define NBLK (NV * BS)   // 1632 partials

// Round-3: round-0 skeleton (ws partials + finalize kernel — proven fastest
// structure) with three cuts:
//  - non-sym blocks: no LDS staging, no staging barrier (ADD path only needs
//    the thread's OWN gt points; computed directly, bit-identical expressions)
//  - sym blocks: staging reuses the same mb loads as the pred transform
//    (p0=tid, p1=tid+256 are exactly the staged q's) -> half the global loads
//  - sym inner loop: 8-q unroll, min chain written as fminf(acc,fminf(d,d))
//    to fuse into v_min3_f32 (24 fma + 4 min3 per point per 8q, vs 32 ops)
// Learned (r1/r2): the 256-MiB ws poison fill (~40us) is unconditional harness
// cost — ws use is free; same-address atomicAdd x1632 costs ~20us — never again.

__global__ __launch_bounds__(256) void partial_kernel(
    const float* __restrict__ pred_r,    // (8,4,4096)
    const float* __restrict__ pred_t,    // (8,3,4096)
    const float* __restrict__ pred_score,// (8,4096)
    const float* __restrict__ gt_r,      // (8,3,3)
    const float* __restrict__ gt_t,      // (8,3)
    const int*   __restrict__ cls_ids,   // (8,)
    const float* __restrict__ model_xyz, // (8,3,400)
    float* __restrict__ partials)        // (1632,)
{
    const int v   = blockIdx.x;   // 0..203
    const int b   = blockIdx.y;   // 0..7
    const int tid = threadIdx.x;  // 0..255
    const int pix = v * STEP;

    __shared__ float4 s_g[NP];    // (gx, gy, gz, gn) per gt point (sym only)
    __shared__ float  s_part[4];

    const int   cls = cls_ids[b];
    const bool  sym = (cls==12)||(cls==15)||(cls==18)||(cls==19)||(cls==20);
    const bool  valid = (cls+1 >= 1) && (cls+1 <= 30); // SELECT_ID = 1..30
    const bool  has2 = (tid < NP - 256);               // tid < 144

    const float* mb = model_xyz + (size_t)b * 3 * NP;

    // ---- this thread's model points (serve BOTH gt staging and pred) ----
    const int p0 = tid;
    const int p1 = has2 ? tid + 256 : tid;
    const float mx0 = mb[p0], my0 = mb[NP+p0], mz0 = mb[2*NP+p0];
    const float mx1 = mb[p1], my1 = mb[NP+p1], mz1 = mb[2*NP+p1];

    // ---- gt transform of own points (needed by both paths) ----
    const float g00 = gt_r[b*9+0], g01 = gt_r[b*9+1], g02 = gt_r[b*9+2];
    const float g10 = gt_r[b*9+3], g11 = gt_r[b*9+4], g12 = gt_r[b*9+5];
    const float g20 = gt_r[b*9+6], g21 = gt_r[b*9+7], g22 = gt_r[b*9+8];
    const float gtx = gt_t[b*3+0], gty = gt_t[b*3+1], gtz = gt_t[b*3+2];

    const float gx0 = g00*mx0 + g01*my0 + g02*mz0 + gtx;
    const float gy0 = g10*mx0 + g11*my0 + g12*mz0 + gty;
    const float gz0 = g20*mx0 + g21*my0 + g22*mz0 + gtz;
    const float gx1 = g00*mx1 + g01*my1 + g02*mz1 + gtx;
    const float gy1 = g10*mx1 + g11*my1 + g12*mz1 + gty;
    const float gz1 = g20*mx1 + g21*my1 + g22*mz1 + gtz;

    if (sym) {  // block-uniform branch: barrier inside is legal
        s_g[p0] = make_float4(gx0, gy0, gz0, gx0*gx0 + gy0*gy0 + gz0*gz0);
        if (has2)
            s_g[p1] = make_float4(gx1, gy1, gz1, gx1*gx1 + gy1*gy1 + gz1*gz1);
    }

    // ---- quaternion -> rotation (uniform per block) ----
    float q0 = pred_r[((size_t)b*4+0)*HW + pix];
    float q1 = pred_r[((size_t)b*4+1)*HW + pix];
    float q2 = pred_r[((size_t)b*4+2)*HW + pix];
    float q3 = pred_r[((size_t)b*4+3)*HW + pix];
    {
        float inv = 1.0f / sqrtf(q0*q0 + q1*q1 + q2*q2 + q3*q3);
        q0 *= inv; q1 *= inv; q2 *= inv; q3 *= inv;
    }
    const float R00 = 1.0f - 2.0f*(q2*q2 + q3*q3);
    const float R01 = 2.0f*q1*q2 - 2.0f*q0*q3;
    const float R02 = 2.0f*q0*q2 + 2.0f*q1*q3;
    const float R10 = 2.0f*q1*q2 + 2.0f*q3*q0;
    const float R11 = 1.0f - 2.0f*(q1*q1 + q3*q3);
    const float R12 = -2.0f*q0*q1 + 2.0f*q2*q3;
    const float R20 = -2.0f*q0*q2 + 2.0f*q1*q3;
    const float R21 = 2.0f*q0*q1 + 2.0f*q2*q3;
    const float R22 = 1.0f - 2.0f*(q1*q1 + q2*q2);

    const float ptx = pred_t[((size_t)b*3+0)*HW + pix];
    const float pty = pred_t[((size_t)b*3+1)*HW + pix];
    const float ptz = pred_t[((size_t)b*3+2)*HW + pix];

    // ---- predicted points ----
    const float px0 = R00*mx0 + R01*my0 + R02*mz0 + ptx;
    const float py0 = R10*mx0 + R11*my0 + R12*mz0 + pty;
    const float pz0 = R20*mx0 + R21*my0 + R22*mz0 + ptz;
    const float px1 = R00*mx1 + R01*my1 + R02*mz1 + ptx;
    const float py1 = R10*mx1 + R11*my1 + R12*mz1 + pty;
    const float pz1 = R20*mx1 + R21*my1 + R22*mz1 + ptz;

    float d2_0 = 0.0f, d2_1 = 0.0f;
    if (sym) {
        __syncthreads();   // s_g ready (sym is block-uniform)
        const float nx0 = -2.0f*px0, ny0 = -2.0f*py0, nz0 = -2.0f*pz0;
        const float pn0 = px0*px0 + py0*py0 + pz0*pz0;
        if (tid < 192) {
            // waves 0..2: two points per thread (lanes 144..191 compute a dup)
            const float nx1 = -2.0f*px1, ny1 = -2.0f*py1, nz1 = -2.0f*pz1;
            const float pn1 = px1*px1 + py1*py1 + pz1*pz1;
            float a01 = 3.4e38f, a23 = 3.4e38f;
            float c01 = 3.4e38f, c23 = 3.4e38f;
            for (int q = 0; q < NP; q += 8) {
                const float4 g0 = s_g[q+0], g1 = s_g[q+1];
                const float4 g2 = s_g[q+2], g3 = s_g[q+3];
                const float4 g4 = s_g[q+4], g5 = s_g[q+5];
                const float4 g6 = s_g[q+6], g7 = s_g[q+7];
                const float d0 = fmaf(nx0, g0.x, fmaf(ny0, g0.y, fmaf(nz0, g0.z, g0.w)));
                const float d1 = fmaf(nx0, g1.x, fmaf(ny0, g1.y, fmaf(nz0, g1.z, g1.w)));
                const float d2 = fmaf(nx0, g2.x, fmaf(ny0, g2.y, fmaf(nz0, g2.z, g2.w)));
                const float d3 = fmaf(nx0, g3.x, fmaf(ny0, g3.y, fmaf(nz0, g3.z, g3.w)));
                const float d4 = fmaf(nx0, g4.x, fmaf(ny0, g4.y, fmaf(nz0, g4.z, g4.w)));
                const float d5 = fmaf(nx0, g5.x, fmaf(ny0, g5.y, fmaf(nz0, g5.z, g5.w)));
                const float d6 = fmaf(nx0, g6.x, fmaf(ny0, g6.y, fmaf(nz0, g6.z, g6.w)));
                const float d7 = fmaf(nx0, g7.x, fmaf(ny0, g7.y, fmaf(nz0, g7.z, g7.w)));
                a01 = fminf(a01, fminf(d0, d1));   // -> v_min3_f32
                a23 = fminf(a23, fminf(d2, d3));
                a01 = fminf(a01, fminf(d4, d5));
                a23 = fminf(a23, fminf(d6, d7));
                const float e0 = fmaf(nx1, g0.x, fmaf(ny1, g0.y, fmaf(nz1, g0.z, g0.w)));
                const float e1 = fmaf(nx1, g1.x, fmaf(ny1, g1.y, fmaf(nz1, g1.z, g1.w)));
                const float e2 = fmaf(nx1, g2.x, fmaf(ny1, g2.y, fmaf(nz1, g2.z, g2.w)));
                const float e3 = fmaf(nx1, g3.x, fmaf(ny1, g3.y, fmaf(nz1, g3.z, g3.w)));
                const float e4 = fmaf(nx1, g4.x, fmaf(ny1, g4.y, fmaf(nz1, g4.z, g4.w)));
                const float e5 = fmaf(nx1, g5.x, fmaf(ny1, g5.y, fmaf(nz1, g5.z, g5.w)));
                const float e6 = fmaf(nx1, g6.x, fmaf(ny1, g6.y, fmaf(nz1, g6.z, g6.w)));
                const float e7 = fmaf(nx1, g7.x, fmaf(ny1, g7.y, fmaf(nz1, g7.z, g7.w)));
                c01 = fminf(c01, fminf(e0, e1));
                c23 = fminf(c23, fminf(e2, e3));
                c01 = fminf(c01, fminf(e4, e5));
                c23 = fminf(c23, fminf(e6, e7));
            }
            d2_0 = fmaxf(pn0 + fminf(a01, a23), 0.0f);
            d2_1 = fmaxf(pn1 + fminf(c01, c23), 0.0f);
        } else {
            // wave 3: single point per thread — half the VALU work
            float a01 = 3.4e38f, a23 = 3.4e38f;
            for (int q = 0; q < NP; q += 8) {
                const float4 g0 = s_g[q+0], g1 = s_g[q+1];
                const float4 g2 = s_g[q+2], g3 = s_g[q+3];
                const float4 g4 = s_g[q+4], g5 = s_g[q+5];
                const float4 g6 = s_g[q+6], g7 = s_g[q+7];
                const float d0 = fmaf(nx0, g0.x, fmaf(ny0, g0.y, fmaf(nz0, g0.z, g0.w)));
                const float d1 = fmaf(nx0, g1.x, fmaf(ny0, g1.y, fmaf(nz0, g1.z, g1.w)));
                const float d2 = fmaf(nx0, g2.x, fmaf(ny0, g2.y, fmaf(nz0, g2.z, g2.w)));
                const float d3 = fmaf(nx0, g3.x, fmaf(ny0, g3.y, fmaf(nz0, g3.z, g3.w)));
                const float d4 = fmaf(nx0, g4.x, fmaf(ny0, g4.y, fmaf(nz0, g4.z, g4.w)));
                const float d5 = fmaf(nx0, g5.x, fmaf(ny0, g5.y, fmaf(nz0, g5.z, g5.w)));
                const float d6 = fmaf(nx0, g6.x, fmaf(ny0, g6.y, fmaf(nz0, g6.z, g6.w)));
                const float d7 = fmaf(nx0, g7.x, fmaf(ny0, g7.y, fmaf(nz0, g7.z, g7.w)));
                a01 = fminf(a01, fminf(d0, d1));
                a23 = fminf(a23, fminf(d2, d3));
                a01 = fminf(a01, fminf(d4, d5));
                a23 = fminf(a23, fminf(d6, d7));
            }
            d2_0 = fmaxf(pn0 + fminf(a01, a23), 0.0f);
            d2_1 = 0.0f;
        }
    } else {
        // ADD path: direct differences against own gt points (no LDS at all)
        float dx = px0 - gx0, dy = py0 - gy0, dz = pz0 - gz0;
        d2_0 = dx*dx + dy*dy + dz*dz;
        dx = px1 - gx1; dy = py1 - gy1; dz = pz1 - gz1;
        d2_1 = dx*dx + dy*dy + dz*dz;
    }
    float local = sqrtf(d2_0) + (has2 ? sqrtf(d2_1) : 0.0f);

    // ---- block reduction (4 waves of 64) ----
    #pragma unroll
    for (int off = 32; off > 0; off >>= 1)
        local += __shfl_down(local, off, 64);
    const int wave = tid >> 6;
    if ((tid & 63) == 0) s_part[wave] = local;
    __syncthreads();
    if (tid == 0) {
        float tot  = s_part[0] + s_part[1] + s_part[2] + s_part[3];
        float mean = tot * (1.0f / NP);                 // add_ij[b,v]
        float ps   = pred_score[(size_t)b*HW + pix];
        float c = 0.0f;
        if (valid)
            c = (mean * ps - 0.01f * logf(ps)) * (1.0f / NBLK);
        partials[b * NV + v] = c;   // unconditional write: no init needed
    }
}

__global__ __launch_bounds__(256) void finalize_kernel(
    const float* __restrict__ partials, float* __restrict__ out)
{
    __shared__ float s_part[4];
    const int tid = threadIdx.x;
    const float4* p4 = reinterpret_cast<const float4*>(partials);
    float local = 0.0f;
    for (int i = tid; i < NBLK / 4; i += 256) {   // 408 float4's
        float4 vv = p4[i];
        local += vv.x + vv.y + vv.z + vv.w;
    }
    #pragma unroll
    for (int off = 32; off > 0; off >>= 1)
        local += __shfl_down(local, off, 64);
    if ((tid & 63) == 0) s_part[tid >> 6] = local;
    __syncthreads();
    if (tid == 0) {
        float vv = s_part[0] + s_part[1] + s_part[2] + s_part[3];
        if (isnan(vv) || isinf(vv)) vv = 0.0f;
        out[0] = vv;   // gadd_loss + 0*gadd == gadd_loss
    }
}

extern "C" void kernel_launch(void* const* d_in, const int* in_sizes, int n_in,
                              void* d_out, int out_size, void* d_ws, size_t ws_size,
                              hipStream_t stream) {
    const float* pred_r     = (const float*)d_in[0];
    const float* pred_t     = (const float*)d_in[1];
    const float* pred_score = (const float*)d_in[2];
    const float* gt_r       = (const float*)d_in[3];
    const float* gt_t       = (const float*)d_in[4];
    const int*   cls_ids    = (const int*)d_in[5];
    const float* model_xyz  = (const float*)d_in[6];
    float* out      = (float*)d_out;
    float* partials = (float*)d_ws;  // 1632 floats, fully overwritten each call

    dim3 grid(NV, BS);
    partial_kernel<<<grid, 256, 0, stream>>>(pred_r, pred_t, pred_score,
                                             gt_r, gt_t, cls_ids, model_xyz, partials);
    finalize_kernel<<<1, 256, 0, stream>>>(partials, out);
}

// Round 4
// 69.520 us; speedup vs baseline: 1.6735x; 1.0111x over previous
//
#include <hip/hip_runtime.h>
#include <math.h>

#define NP 400
#define NV 204
#define STEP 20
#define HW 4096
#define BS 8
#define NBLK (NV * BS)   // 1632 partials

// Round-4: attack the sym inner loop's DS-issue bound.
// Prior rounds established:
//  - ~60us/iter is harness-fixed (256-MiB ws poison fill ~40us unconditional,
//    input restores, launch gaps). ws use is free; same-address atomics cost
//    ~20us (r2); global-load q-scan is latency-bound (r1, 53us).
//  - sym loop was DS-bound: 400 broadcast ds_read_b128 per wave x 4 waves x
//    ~12cyc on the shared per-CU DS pipe = ~19k cyc (~8us) vs 5.6k cyc VALU.
// Fix: lane-spread q-scan. 4-lane group owns 6-7 points (p = partition of 400
// over 64 groups); lane (tid&3) scans q = sub (mod 4). Each ds_read_b128 now
// serves 4 distinct q's per wave -> 100 reads/wave (4x cut). Group-min
// recombined with 2 shfl_xor + fminf (exact). Pred points staged in s_p so
// lanes fetch their group's p's by broadcast. New balance: DS ~4.8k cyc/CU,
// VALU ~5k cyc/SIMD -> VALU-bound ~2.1us.

__global__ __launch_bounds__(256) void partial_kernel(
    const float* __restrict__ pred_r,    // (8,4,4096)
    const float* __restrict__ pred_t,    // (8,3,4096)
    const float* __restrict__ pred_score,// (8,4096)
    const float* __restrict__ gt_r,      // (8,3,3)
    const float* __restrict__ gt_t,      // (8,3)
    const int*   __restrict__ cls_ids,   // (8,)
    const float* __restrict__ model_xyz, // (8,3,400)
    float* __restrict__ partials)        // (1632,)
{
    const int v   = blockIdx.x;   // 0..203
    const int b   = blockIdx.y;   // 0..7
    const int tid = threadIdx.x;  // 0..255
    const int pix = v * STEP;

    __shared__ float4 s_g[NP];    // (gx, gy, gz, |g|^2)   (sym only)
    __shared__ float4 s_p[NP];    // (px, py, pz, |p|^2)   (sym only)
    __shared__ float  s_part[4];

    const int   cls = cls_ids[b];
    const bool  sym = (cls==12)||(cls==15)||(cls==18)||(cls==19)||(cls==20);
    const bool  valid = (cls+1 >= 1) && (cls+1 <= 30); // SELECT_ID = 1..30
    const bool  has2 = (tid < NP - 256);               // tid < 144

    const float* mb = model_xyz + (size_t)b * 3 * NP;

    // ---- this thread's model points (serve gt staging, pred, ADD path) ----
    const int p0 = tid;
    const int p1 = has2 ? tid + 256 : tid;
    const float mx0 = mb[p0], my0 = mb[NP+p0], mz0 = mb[2*NP+p0];
    const float mx1 = mb[p1], my1 = mb[NP+p1], mz1 = mb[2*NP+p1];

    // ---- gt transform of own points ----
    const float g00 = gt_r[b*9+0], g01 = gt_r[b*9+1], g02 = gt_r[b*9+2];
    const float g10 = gt_r[b*9+3], g11 = gt_r[b*9+4], g12 = gt_r[b*9+5];
    const float g20 = gt_r[b*9+6], g21 = gt_r[b*9+7], g22 = gt_r[b*9+8];
    const float gtx = gt_t[b*3+0], gty = gt_t[b*3+1], gtz = gt_t[b*3+2];

    const float gx0 = g00*mx0 + g01*my0 + g02*mz0 + gtx;
    const float gy0 = g10*mx0 + g11*my0 + g12*mz0 + gty;
    const float gz0 = g20*mx0 + g21*my0 + g22*mz0 + gtz;
    const float gx1 = g00*mx1 + g01*my1 + g02*mz1 + gtx;
    const float gy1 = g10*mx1 + g11*my1 + g12*mz1 + gty;
    const float gz1 = g20*mx1 + g21*my1 + g22*mz1 + gtz;

    // ---- quaternion -> rotation (uniform per block) ----
    float q0 = pred_r[((size_t)b*4+0)*HW + pix];
    float q1 = pred_r[((size_t)b*4+1)*HW + pix];
    float q2 = pred_r[((size_t)b*4+2)*HW + pix];
    float q3 = pred_r[((size_t)b*4+3)*HW + pix];
    {
        float inv = 1.0f / sqrtf(q0*q0 + q1*q1 + q2*q2 + q3*q3);
        q0 *= inv; q1 *= inv; q2 *= inv; q3 *= inv;
    }
    const float R00 = 1.0f - 2.0f*(q2*q2 + q3*q3);
    const float R01 = 2.0f*q1*q2 - 2.0f*q0*q3;
    const float R02 = 2.0f*q0*q2 + 2.0f*q1*q3;
    const float R10 = 2.0f*q1*q2 + 2.0f*q3*q0;
    const float R11 = 1.0f - 2.0f*(q1*q1 + q3*q3);
    const float R12 = -2.0f*q0*q1 + 2.0f*q2*q3;
    const float R20 = -2.0f*q0*q2 + 2.0f*q1*q3;
    const float R21 = 2.0f*q0*q1 + 2.0f*q2*q3;
    const float R22 = 1.0f - 2.0f*(q1*q1 + q2*q2);

    const float ptx = pred_t[((size_t)b*3+0)*HW + pix];
    const float pty = pred_t[((size_t)b*3+1)*HW + pix];
    const float ptz = pred_t[((size_t)b*3+2)*HW + pix];

    // ---- predicted points ----
    const float px0 = R00*mx0 + R01*my0 + R02*mz0 + ptx;
    const float py0 = R10*mx0 + R11*my0 + R12*mz0 + pty;
    const float pz0 = R20*mx0 + R21*my0 + R22*mz0 + ptz;
    const float px1 = R00*mx1 + R01*my1 + R02*mz1 + ptx;
    const float py1 = R10*mx1 + R11*my1 + R12*mz1 + pty;
    const float pz1 = R20*mx1 + R21*my1 + R22*mz1 + ptz;

    float local = 0.0f;
    if (sym) {   // block-uniform branch: barrier inside is legal
        s_g[p0] = make_float4(gx0, gy0, gz0, gx0*gx0 + gy0*gy0 + gz0*gz0);
        s_p[p0] = make_float4(px0, py0, pz0, px0*px0 + py0*py0 + pz0*pz0);
        if (has2) {
            s_g[p1] = make_float4(gx1, gy1, gz1, gx1*gx1 + gy1*gy1 + gz1*gz1);
            s_p[p1] = make_float4(px1, py1, pz1, px1*px1 + py1*py1 + pz1*pz1);
        }
        __syncthreads();

        // 4-lane group owns points [pstart, pstart+pcount); lane sub scans
        // q = sub (mod 4). 64 groups x {6,7} points partition [0,400).
        const int sub    = tid & 3;
        const int grp    = tid >> 2;
        const int pstart = (25 * grp) >> 2;              // floor(grp*6.25)
        const int pcount = ((25 * (grp + 1)) >> 2) - pstart;  // 6 or 7

        float nx[7], ny[7], nz[7], pn[7], acc[7];
        #pragma unroll
        for (int j = 0; j < 7; ++j) {
            const int pp = pstart + (j < pcount ? j : 0);  // dup pad, masked at sum
            const float4 P = s_p[pp];
            nx[j] = -2.0f * P.x;
            ny[j] = -2.0f * P.y;
            nz[j] = -2.0f * P.z;
            pn[j] = P.w;
            acc[j] = 3.4e38f;
        }

        for (int qb = 0; qb < NP; qb += 8) {
            const float4 ga = s_g[qb + sub];        // 4 distinct q's per wave
            const float4 gb = s_g[qb + 4 + sub];
            #pragma unroll
            for (int j = 0; j < 7; ++j) {
                const float da = fmaf(nx[j], ga.x, fmaf(ny[j], ga.y, fmaf(nz[j], ga.z, ga.w)));
                const float db = fmaf(nx[j], gb.x, fmaf(ny[j], gb.y, fmaf(nz[j], gb.z, gb.w)));
                acc[j] = fminf(acc[j], fminf(da, db));   // -> v_min3_f32
            }
        }

        // combine the 4 q-chunks within each lane group (exact: min reassoc)
        #pragma unroll
        for (int j = 0; j < 7; ++j) {
            float m = acc[j];
            m = fminf(m, __shfl_xor(m, 1, 64));
            m = fminf(m, __shfl_xor(m, 2, 64));
            if (sub == 0 && j < pcount)
                local += sqrtf(fmaxf(pn[j] + m, 0.0f));
        }
    } else {
        // ADD path: direct differences against own gt points (no LDS at all)
        float dx = px0 - gx0, dy = py0 - gy0, dz = pz0 - gz0;
        const float d2_0 = dx*dx + dy*dy + dz*dz;
        dx = px1 - gx1; dy = py1 - gy1; dz = pz1 - gz1;
        const float d2_1 = dx*dx + dy*dy + dz*dz;
        local = sqrtf(d2_0) + (has2 ? sqrtf(d2_1) : 0.0f);
    }

    // ---- block reduction (4 waves of 64) ----
    #pragma unroll
    for (int off = 32; off > 0; off >>= 1)
        local += __shfl_down(local, off, 64);
    const int wave = tid >> 6;
    if ((tid & 63) == 0) s_part[wave] = local;
    __syncthreads();
    if (tid == 0) {
        float tot  = s_part[0] + s_part[1] + s_part[2] + s_part[3];
        float mean = tot * (1.0f / NP);                 // add_ij[b,v]
        float ps   = pred_score[(size_t)b*HW + pix];
        float c = 0.0f;
        if (valid)
            c = (mean * ps - 0.01f * logf(ps)) * (1.0f / NBLK);
        partials[b * NV + v] = c;   // unconditional write: no init needed
    }
}

__global__ __launch_bounds__(256) void finalize_kernel(
    const float* __restrict__ partials, float* __restrict__ out)
{
    __shared__ float s_part[4];
    const int tid = threadIdx.x;
    const float4* p4 = reinterpret_cast<const float4*>(partials);
    float local = 0.0f;
    for (int i = tid; i < NBLK / 4; i += 256) {   // 408 float4's
        float4 vv = p4[i];
        local += vv.x + vv.y + vv.z + vv.w;
    }
    #pragma unroll
    for (int off = 32; off > 0; off >>= 1)
        local += __shfl_down(local, off, 64);
    if ((tid & 63) == 0) s_part[tid >> 6] = local;
    __syncthreads();
    if (tid == 0) {
        float vv = s_part[0] + s_part[1] + s_part[2] + s_part[3];
        if (isnan(vv) || isinf(vv)) vv = 0.0f;
        out[0] = vv;   // gadd_loss + 0*gadd == gadd_loss
    }
}

extern "C" void kernel_launch(void* const* d_in, const int* in_sizes, int n_in,
                              void* d_out, int out_size, void* d_ws, size_t ws_size,
                              hipStream_t stream) {
    const float* pred_r     = (const float*)d_in[0];
    const float* pred_t     = (const float*)d_in[1];
    const float* pred_score = (const float*)d_in[2];
    const float* gt_r       = (const float*)d_in[3];
    const float* gt_t       = (const float*)d_in[4];
    const int*   cls_ids    = (const int*)d_in[5];
    const float* model_xyz  = (const float*)d_in[6];
    float* out      = (float*)d_out;
    float* partials = (float*)d_ws;  // 1632 floats, fully overwritten each call

    dim3 grid(NV, BS);
    partial_kernel<<<grid, 256, 0, stream>>>(pred_r, pred_t, pred_score,
                                             gt_r, gt_t, cls_ids, model_xyz, partials);
    finalize_kernel<<<1, 256, 0, stream>>>(partials, out);
}